// Round 5
// baseline (209.154 us; speedup 1.0000x reference)
//
#include <hip/hip_runtime.h>

// RoiAlign fused: level-select + crop_and_resize(7x7 bilinear, extrap 0)
// feat0: [B,256,256,256] f32 NHWC ; feat1: [B,128,128,256] f32 ; rois: [B,R,5]
// out: [B,R,7,7,256] f32
//
// Mapping: one wave (64 lanes) per (box n, pool row i); lane -> 4 channels
// via float4. ALL 28 corner loads are issued branch-free up front (phase 1),
// then bilinear compute + stores (phase 2).
//
// NEW (R5): chunked bijective XCD swizzle (T1/m204). Default dispatch
// round-robins consecutive blocks across the 8 XCDs, so a box's 7 row-waves
// (~2 consecutive blocks) land on different XCDs and shared feature rows are
// fetched from HBM once PER XCD (non-coherent L2s). The swizzle gives each
// XCD a contiguous chunk of logical blocks -> box-local L2 reuse.

#define POOL 7
#define NCH 256
#define NXCD 8

// native vector type for nontemporal store (HIP float4 class is rejected)
typedef float nfloat4 __attribute__((ext_vector_type(4)));

__global__ __launch_bounds__(256) void roialign_kernel(
    const float* __restrict__ feat0,
    const float* __restrict__ feat1,
    const float* __restrict__ rois,
    float* __restrict__ out,
    int NB, int R) // NB = B*R
{
    // ---- chunked bijective XCD swizzle (m204): consecutive logical blocks
    // map to the same XCD; hw blockIdx round-robins XCDs.
    int nblk = gridDim.x;
    int q = nblk / NXCD, r = nblk % NXCD;
    int xcd = blockIdx.x % NXCD;
    int idx = blockIdx.x / NXCD;
    int logical = (xcd < r ? xcd * (q + 1) : r * (q + 1) + (xcd - r) * q) + idx;

    int t = logical * blockDim.x + threadIdx.x;
    int lane = t & 63;          // channel group: channels [4*lane, 4*lane+3]
    int wid  = t >> 6;          // n*7 + i   (wave-uniform)
    int n    = wid / 7;
    if (n >= NB) return;
    int i = wid - n * 7;

    const float* roi = rois + (size_t)n * 5;
    float y1 = roi[0], x1 = roi[1], y2 = roi[2], x2 = roi[3];

    // level select on RAW box coords (before normalization), matching ref
    bool lvl = (y2 - y1 > 48.0f) || (x2 - x1 > 48.0f);
    const float* feat = lvl ? feat1 : feat0;
    int H = lvl ? 128 : 256;
    int W = H;
    int b = n / R;

    const float inv_img = 1.0f / 1024.0f;
    float y1n = y1 * inv_img, y2n = y2 * inv_img;
    float x1n = x1 * inv_img, x2n = x2 * inv_img;

    float Hm1 = (float)(H - 1), Wm1 = (float)(W - 1);

    // ys = (y1n + (i/6)*(y2n-y1n)) * (H-1)   -- same op order as reference
    float ry = (float)i / 6.0f;
    float ys = (y1n + ry * (y2n - y1n)) * Hm1;
    float y0f = floorf(ys);
    float wy  = ys - y0f;
    int y0 = (int)fminf(fmaxf(y0f,        0.0f), Hm1);
    int yp = (int)fminf(fmaxf(y0f + 1.0f, 0.0f), Hm1);
    bool vy = (ys >= 0.0f) && (ys <= Hm1);

    size_t plane = (size_t)b * H * W;
    int coff = lane * 4;
    const float* row0 = feat + (plane + (size_t)y0 * W) * NCH + coff;
    const float* row1 = feat + (plane + (size_t)yp * W) * NCH + coff;

    float* orow = out + ((size_t)n * 49 + (size_t)i * POOL) * NCH + coff;

    float wy1 = 1.0f - wy;

    // ---- phase 0: x geometry for all j (branch-free, wave-uniform) ----
    float wxv[POOL];
    bool  vxv[POOL];
    int   x0v[POOL], xpv[POOL];
    #pragma unroll
    for (int j = 0; j < POOL; ++j) {
        float rx = (float)j / 6.0f;                 // exact same rounding as ref
        float xs = (x1n + rx * (x2n - x1n)) * Wm1;
        float x0f = floorf(xs);
        wxv[j] = xs - x0f;
        x0v[j] = (int)fminf(fmaxf(x0f,        0.0f), Wm1);
        xpv[j] = (int)fminf(fmaxf(x0f + 1.0f, 0.0f), Wm1);
        vxv[j] = (xs >= 0.0f) && (xs <= Wm1);
    }

    // ---- phase 1: issue all 28 corner loads (independent, max MLP) ----
    float4 v00[POOL], v01[POOL], v10[POOL], v11[POOL];
    #pragma unroll
    for (int j = 0; j < POOL; ++j) {
        v00[j] = *(const float4*)(row0 + (size_t)x0v[j] * NCH);
        v01[j] = *(const float4*)(row0 + (size_t)xpv[j] * NCH);
        v10[j] = *(const float4*)(row1 + (size_t)x0v[j] * NCH);
        v11[j] = *(const float4*)(row1 + (size_t)xpv[j] * NCH);
    }

    // ---- phase 2: bilinear + store ----
    #pragma unroll
    for (int j = 0; j < POOL; ++j) {
        float wx  = wxv[j];
        float wx1 = 1.0f - wx;
        float4 a = v00[j], bq = v01[j], c = v10[j], d = v11[j];
        float4 o;
        {
            float tx = a.x * wx1 + bq.x * wx;
            float bx = c.x * wx1 + d.x * wx;
            o.x = tx * wy1 + bx * wy;
            float ty = a.y * wx1 + bq.y * wx;
            float by = c.y * wx1 + d.y * wx;
            o.y = ty * wy1 + by * wy;
            float tz = a.z * wx1 + bq.z * wx;
            float bz = c.z * wx1 + d.z * wx;
            o.z = tz * wy1 + bz * wy;
            float tw = a.w * wx1 + bq.w * wx;
            float bw = c.w * wx1 + d.w * wx;
            o.w = tw * wy1 + bw * wy;
        }
        if (!(vy && vxv[j])) { o.x = 0.0f; o.y = 0.0f; o.z = 0.0f; o.w = 0.0f; }

        // write-once output: nontemporal, keep L2/L3 for feature maps
        nfloat4 ov;
        ov.x = o.x; ov.y = o.y; ov.z = o.z; ov.w = o.w;
        __builtin_nontemporal_store(ov, (nfloat4*)(orow + (size_t)j * NCH));
    }
}

extern "C" void kernel_launch(void* const* d_in, const int* in_sizes, int n_in,
                              void* d_out, int out_size, void* d_ws, size_t ws_size,
                              hipStream_t stream) {
    const float* feat0 = (const float*)d_in[0];
    const float* feat1 = (const float*)d_in[1];
    const float* rois  = (const float*)d_in[2];
    float* out = (float*)d_out;

    // B from feat0 size [B,256,256,256]; R from rois size [B,R,5]
    int B  = in_sizes[0] / (256 * 256 * 256);
    int NB = in_sizes[2] / 5;        // B*R boxes
    int R  = NB / B;

    // one wave per (box, pool row): NB*7 waves, 64 lanes each
    long long threads = (long long)NB * POOL * 64;
    int block = 256;
    int grid = (int)((threads + block - 1) / block);
    roialign_kernel<<<grid, block, 0, stream>>>(feat0, feat1, rois, out, NB, R);
}